// Round 5
// baseline (2065.610 us; speedup 1.0000x reference)
//
#include <hip/hip_runtime.h>

#define EDIM 128
#define NE   1024
#define RPB  256          // rows per block = threads per block
#define KT   32           // codes per LDS W-tile
#define NT   (NE / KT)    // 32 tiles

// Bit-exact reproduction of numpy fp32 (locked in round 2, absmax 0.0):
//   d = (sum(x*x,1,keepdims) + sum(W*W,1)) - 2*matmul(x, W.T)
//   idx = argmin(d,1) (first index on ties); z_q = W[idx]
//  - sums: numpy pairwise 8-accumulator stride-8 pattern, mul then add
//  - matmul: sequential-j fmaf chain per (row,k)  [k-tiling does not split j]
//  - d: fl32(fl32(xx + wk2) - fl32(2*dot)), strict < argmin, k ascending
// Round-5: 4 waves/SIMD occupancy; W double-buffered in LDS via
// global_load_lds(16B); wave-uniform ds_read_b128 broadcasts (imm offsets);
// x streamed from global one 64B line per body (single fetch per tile-pass).

typedef __attribute__((address_space(3))) void       lds_t;
typedef const __attribute__((address_space(1))) void gm_t;

__global__ __launch_bounds__(256, 4) void vq_v5(
    const float* __restrict__ x, const float* __restrict__ W,
    float* __restrict__ zq, float* __restrict__ idxout)
{
#pragma clang fp contract(off)
    __shared__ float  swsq[NE];          // 4 KB
    __shared__ float4 wt[2][KT * 32];    // 2 x 16 KB, double-buffered W tiles
    __shared__ int    sbest[RPB];        // 1 KB

    const int tid = threadIdx.x;
    const long long row0 = (long long)blockIdx.x * RPB;
    const long long row  = row0 + tid;

    const float4* x4 = reinterpret_cast<const float4*>(x);
    const float4* W4 = reinterpret_cast<const float4*>(W);

    // ---- stage W tile 0 (async, direct-to-LDS, 16 B/lane) ----
    #pragma unroll
    for (int i = 0; i < 4; ++i) {
        __builtin_amdgcn_global_load_lds(
            (gm_t*)(W4 + i * 256 + tid),
            (lds_t*)(&wt[0][i * 256 + tid]), 16, 0, 0);
    }

    // ---- swsq[k] = np.sum(W*W,1): numpy pairwise 8-acc pattern (4 codes/thread) ----
    for (int k = tid; k < NE; k += RPB) {
        const float4* wr = W4 + (size_t)k * 32;
        float4 A = wr[0], B = wr[1];
        float r0 = A.x * A.x, r1 = A.y * A.y, r2 = A.z * A.z, r3 = A.w * A.w;
        float r4 = B.x * B.x, r5 = B.y * B.y, r6 = B.z * B.z, r7 = B.w * B.w;
        #pragma unroll
        for (int i = 2; i < 32; i += 2) {
            float4 C = wr[i], D = wr[i + 1];
            r0 += C.x * C.x; r1 += C.y * C.y; r2 += C.z * C.z; r3 += C.w * C.w;
            r4 += D.x * D.x; r5 += D.y * D.y; r6 += D.z * D.z; r7 += D.w * D.w;
        }
        swsq[k] = ((r0 + r1) + (r2 + r3)) + ((r4 + r5) + (r6 + r7));
    }

    // ---- xx = np.sum(x*x,1): same pairwise 8-acc pattern (from global; L1-warm) ----
    float xxv;
    {
        const float4* xr = x4 + row * 32;
        float4 A = xr[0], B = xr[1];
        float r0 = A.x * A.x, r1 = A.y * A.y, r2 = A.z * A.z, r3 = A.w * A.w;
        float r4 = B.x * B.x, r5 = B.y * B.y, r6 = B.z * B.z, r7 = B.w * B.w;
        #pragma unroll
        for (int i = 2; i < 32; i += 2) {
            float4 C = xr[i], D = xr[i + 1];
            r0 += C.x * C.x; r1 += C.y * C.y; r2 += C.z * C.z; r3 += C.w * C.w;
            r4 += D.x * D.x; r5 += D.y * D.y; r6 += D.z * D.z; r7 += D.w * D.w;
        }
        xxv = ((r0 + r1) + (r2 + r3)) + ((r4 + r5) + (r6 + r7));
    }

    __syncthreads();   // drains tile-0 stage (vmcnt) + swsq ds_writes

    // ---- main loop over 32-code W tiles ----
    float dbest = 3.4e38f;
    int   bestk = 0;

    #pragma unroll 1
    for (int t = 0; t < NT; ++t) {
        const int buf = t & 1;

        // prefetch next tile into the other buffer (overlaps with compute)
        if (t + 1 < NT) {
            #pragma unroll
            for (int i = 0; i < 4; ++i) {
                __builtin_amdgcn_global_load_lds(
                    (gm_t*)(W4 + (size_t)(t + 1) * (KT * 32) + i * 256 + tid),
                    (lds_t*)(&wt[buf ^ 1][i * 256 + tid]), 16, 0, 0);
            }
        }

        const float4* wtile = wt[buf];
        float acc[KT];
        #pragma unroll
        for (int c = 0; c < KT; ++c) acc[c] = 0.f;

        #pragma unroll 1
        for (int jo = 0; jo < 8; ++jo) {
            // one 64-B cache line of x per body, fetched once
            float4 a0 = x4[row * 32 + jo * 4 + 0];
            float4 a1 = x4[row * 32 + jo * 4 + 1];
            float4 a2 = x4[row * 32 + jo * 4 + 2];
            float4 a3 = x4[row * 32 + jo * 4 + 3];
            #pragma unroll
            for (int c = 0; c < KT; ++c) {
                // wave-uniform LDS broadcasts, imm offsets; j ascending per code
                float4 w0 = wtile[c * 32 + jo * 4 + 0];
                acc[c] = fmaf(a0.x, w0.x, acc[c]);
                acc[c] = fmaf(a0.y, w0.y, acc[c]);
                acc[c] = fmaf(a0.z, w0.z, acc[c]);
                acc[c] = fmaf(a0.w, w0.w, acc[c]);
                float4 w1 = wtile[c * 32 + jo * 4 + 1];
                acc[c] = fmaf(a1.x, w1.x, acc[c]);
                acc[c] = fmaf(a1.y, w1.y, acc[c]);
                acc[c] = fmaf(a1.z, w1.z, acc[c]);
                acc[c] = fmaf(a1.w, w1.w, acc[c]);
                float4 w2 = wtile[c * 32 + jo * 4 + 2];
                acc[c] = fmaf(a2.x, w2.x, acc[c]);
                acc[c] = fmaf(a2.y, w2.y, acc[c]);
                acc[c] = fmaf(a2.z, w2.z, acc[c]);
                acc[c] = fmaf(a2.w, w2.w, acc[c]);
                float4 w3 = wtile[c * 32 + jo * 4 + 3];
                acc[c] = fmaf(a3.x, w3.x, acc[c]);
                acc[c] = fmaf(a3.y, w3.y, acc[c]);
                acc[c] = fmaf(a3.z, w3.z, acc[c]);
                acc[c] = fmaf(a3.w, w3.w, acc[c]);
            }
        }

        // fold argmin for this tile (k ascending, strict < keeps first index)
        #pragma unroll
        for (int c = 0; c < KT; ++c) {
            float t1 = xxv + swsq[t * KT + c];     // fl(xx + wk2)
            float d  = t1 - (acc[c] + acc[c]);     // fl(t1 - fl(2*dot))
            if (d < dbest) { dbest = d; bestk = t * KT + c; }
        }

        __syncthreads();   // next tile staged (drains vmcnt) + release buf
    }

    sbest[tid] = bestk;
    idxout[row] = (float)bestk;
    __syncthreads();

    // ---- z_q gather (coalesced float4; bit-exact copy of W rows; W is L2-hot) ----
    float4* zq4 = reinterpret_cast<float4*>(zq);
    for (int i = tid; i < RPB * 32; i += RPB) {
        int r = i >> 5, c4 = i & 31;
        zq4[row0 * 32 + i] = W4[(size_t)sbest[r] * 32 + c4];
    }
}

extern "C" void kernel_launch(void* const* d_in, const int* in_sizes, int n_in,
                              void* d_out, int out_size, void* d_ws, size_t ws_size,
                              hipStream_t stream) {
    (void)n_in; (void)out_size; (void)d_ws; (void)ws_size;
    const float* x = (const float*)d_in[0];
    const float* W = (const float*)d_in[1];
    const int Nrows = in_sizes[0] / EDIM;           // 262144

    float* zqp    = (float*)d_out;
    float* idxout = zqp + (size_t)Nrows * EDIM;     // indices stored as float values

    vq_v5<<<dim3(Nrows / RPB), dim3(RPB), 0, stream>>>(x, W, zqp, idxout);
}